// Round 3
// baseline (180.261 us; speedup 1.0000x reference)
//
#include <hip/hip_runtime.h>

#define WIDTH 2048
#define N_LAYERS 24
#define NUM_NEURONS ((N_LAYERS + 1) * WIDTH)
#define NB 256           // 1 block/CU
#define NT 1024          // 16 waves: 0-7 stream, 8-15 poll
#define RPB 8            // rows per block
#define HC 1024          // half-row cols owned by one wave
#define LAYER_ELEMS ((size_t)WIDTH * WIDTH)

typedef unsigned long long u64;
#define WS_NEEDED (NUM_NEURONS * sizeof(u64))
#define WS_EPOCH_NEEDED (WS_NEEDED + 64)
#define MAGIC_V 0x7E57C0DE5EED0001ull
#define SB0() __builtin_amdgcn_sched_barrier(0)

// ---- dataflow primitives: (tag<<32 | f32bits) in one 8B agent atomic ----
__device__ __forceinline__ u64 vload(const u64* p) {
    return __hip_atomic_load(p, __ATOMIC_RELAXED, __HIP_MEMORY_SCOPE_AGENT);
}
__device__ __forceinline__ void publish(u64* p, float f, unsigned E) {
    union { float f; unsigned u; } c; c.f = f;
    __hip_atomic_store(p, ((u64)E << 32) | (u64)c.u, __ATOMIC_RELAXED,
                       __HIP_MEMORY_SCOPE_AGENT);
}

// Async global->LDS staging (no dest registers; regalloc-proof).
__device__ __forceinline__ void gload_lds16(const void* g, void* l) {
    __builtin_amdgcn_global_load_lds(
        (const __attribute__((address_space(1))) void*)g,
        (__attribute__((address_space(3))) void*)l, 16, 0, 0);
}

// Stage one wave-slice (row r, half h): 4KB W + 4KB M, 8 gloads.
__device__ __forceinline__ void stage_slice(const float* Wl, const float* Ml,
                                            float* bw, float* bm,
                                            int r, int h, int lane) {
    const float* wsrc = Wl + (size_t)r * WIDTH + h * HC + lane * 4;
    const float* msrc = Ml + (size_t)r * WIDTH + h * HC + lane * 4;
    char* wdst = (char*)bw + lane * 16;
    char* mdst = (char*)bm + lane * 16;
#pragma unroll
    for (int i = 0; i < 4; ++i) {
        gload_lds16(wsrc + i * 256, wdst + i * 1024);
        gload_lds16(msrc + i * 256, mdst + i * 1024);
    }
}

// prep: idempotent workspace init (early-outs after first launch).
__global__ __launch_bounds__(256) void prep(u64* __restrict__ vals) {
    u64* ctrl = vals + NUM_NEURONS;   // [0]=magic, [1]=done
    if (__hip_atomic_load(&ctrl[0], __ATOMIC_RELAXED,
                          __HIP_MEMORY_SCOPE_AGENT) == MAGIC_V)
        return;
    int i = blockIdx.x * blockDim.x + threadIdx.x;
    int stride = gridDim.x * blockDim.x;
    for (int e = i; e < NUM_NEURONS; e += stride)
        __hip_atomic_store(&vals[e], 0ull, __ATOMIC_RELAXED,
                           __HIP_MEMORY_SCOPE_AGENT);
    if (i == 0) {
        __hip_atomic_store(&ctrl[1], 0ull, __ATOMIC_RELAXED,
                           __HIP_MEMORY_SCOPE_AGENT);
        __hip_atomic_store(&ctrl[0], MAGIC_V, __ATOMIC_RELAXED,
                           __HIP_MEMORY_SCOPE_AGENT);
    }
}

__global__ __launch_bounds__(NT, 4) void mlp_flow(
    const float* __restrict__ x,
    const float* __restrict__ W,
    const float* __restrict__ M,
    const float* __restrict__ B,
    const int*   __restrict__ IDX,
    u64* __restrict__ vals,          // [NUM_NEURONS] (tag,value)
    u64* __restrict__ ctrl,          // epoch ctrl block, or nullptr (legacy)
    float* __restrict__ out)
{
    __shared__ float bufW[16][HC];   // 16 x 4KB
    __shared__ float bufM[16][HC];   // 16 x 4KB
    __shared__ float v_lds[WIDTH];   // 8KB
    __shared__ float wsum[16];

    const int t    = threadIdx.x;
    const int w    = t >> 6;          // wave 0..15
    const int lane = t & 63;
    const int h    = w & 1;           // K-half for the dot (all waves)
    const int bid  = blockIdx.x;
    const bool streamw = (w < 8);     // waves 0-7: stream; 8-15: poll
    const size_t block_off = (size_t)bid * RPB * WIDTH;

    // ---- epoch: E = launch index + 1, from persistent done-counter ----
    unsigned E = 1u;
    if (ctrl) {
        u64 d = vload(&ctrl[1]);
        E = (unsigned)(d >> 8) + 1u;   // done == 256 * launches_completed
    }

    // ---- prologue: zero out slice; once performed, publish input slice ----
    if (t < RPB)
        __hip_atomic_store(out + bid * RPB + t, 0.0f, __ATOMIC_RELAXED,
                           __HIP_MEMORY_SCOPE_AGENT);
    asm volatile("s_waitcnt vmcnt(0)" ::: "memory");
    if (t < RPB) {
        int g = bid * RPB + t;
        publish(vals + g, x[g], E);
    }

    // ---- wave-0 register-carried output scalars (layer 0) ----
    int   myidx = (t < RPB) ? IDX[bid * RPB + t] : 0;
    float bias  = (t < RPB) ? B[bid * RPB + t]   : 0.0f;

    // ---- poll-wave slot + layer-0 index prefetch ----
    const int pj = (w & 7) * 256 + lane * 4;   // v-slot (poll waves)
    int4 I4; I4.x = I4.y = I4.z = I4.w = 0;
    if (!streamw) I4 = *(const int4*)(IDX + pj);

    // ---- stream waves: issue layer-0 slices (own + partner w+8) ----
    SB0();
    if (streamw) {
        const float* Wl = W + block_off;
        const float* Ml = M + block_off;
        stage_slice(Wl, Ml, bufW[w],     bufM[w],     w >> 1,       w & 1, lane);
        stage_slice(Wl, Ml, bufW[w + 8], bufM[w + 8], (w >> 1) + 4, w & 1, lane);
    }
    SB0();

    for (int l = 0; l < N_LAYERS; ++l) {
        // ---- A: this layer's slices resident. Only stream waves carry
        //      vmcnt; poll waves arrive with an empty counter. ----
        if (streamw) { asm volatile("s_waitcnt vmcnt(0)" ::: "memory"); }
        SB0();
        __builtin_amdgcn_s_barrier();            // B1: slices visible

        // ---- B: copy own slice LDS -> registers (R15 chunk order) ----
        float4 wc[4], mc[4];
        {
            const float4* Wt = (const float4*)bufW[w];
            const float4* Mt = (const float4*)bufM[w];
#pragma unroll
            for (int i = 0; i < 4; ++i) {
                wc[i] = Wt[lane + i * 64];
                mc[i] = Mt[lane + i * 64];
            }
        }
        asm volatile("s_waitcnt lgkmcnt(0)" ::: "memory");
        SB0();
        __builtin_amdgcn_s_barrier();            // B2: LDS free for restage

        // ---- C: stream waves issue next layer; poll waves gather v ----
        if (streamw) {
            if (l + 1 < N_LAYERS) {
                const float* Wl = W + (size_t)(l + 1) * LAYER_ELEMS + block_off;
                const float* Ml = M + (size_t)(l + 1) * LAYER_ELEMS + block_off;
                stage_slice(Wl, Ml, bufW[w],     bufM[w],     w >> 1,       w & 1, lane);
                stage_slice(Wl, Ml, bufW[w + 8], bufM[w + 8], (w >> 1) + 4, w & 1, lane);
            }
        } else {
            // poll 4 values; retries drain only THIS wave's loads (cheap)
            const u64* p0 = vals + I4.x;
            const u64* p1 = vals + I4.y;
            const u64* p2 = vals + I4.z;
            const u64* p3 = vals + I4.w;
            u64 a = vload(p0), b = vload(p1), c = vload(p2), d = vload(p3);
            while (((unsigned)(a >> 32) != E) | ((unsigned)(b >> 32) != E) |
                   ((unsigned)(c >> 32) != E) | ((unsigned)(d >> 32) != E)) {
                __builtin_amdgcn_s_sleep(1);
                a = vload(p0); b = vload(p1); c = vload(p2); d = vload(p3);
            }
            union { unsigned u; float f; } ca, cb, cc, cd;
            ca.u = (unsigned)a; cb.u = (unsigned)b;
            cc.u = (unsigned)c; cd.u = (unsigned)d;
            float4 vv; vv.x = ca.f; vv.y = cb.f; vv.z = cc.f; vv.w = cd.f;
            *(float4*)(v_lds + pj) = vv;
            if (l + 1 < N_LAYERS)
                I4 = *(const int4*)(IDX + (l + 1) * WIDTH + pj);
        }
        // wave-0 scalar prefetch for next layer (t<RPB lives in wave 0)
        int   myidx_nxt = myidx;
        float bias_nxt  = bias;
        if (t < RPB && l + 1 < N_LAYERS) {
            myidx_nxt = IDX[(l + 1) * WIDTH + bid * RPB + t];
            bias_nxt  = B[(l + 1) * WIDTH + bid * RPB + t];
        }
        asm volatile("s_waitcnt lgkmcnt(0)" ::: "memory");   // v_lds committed
        SB0();
        __builtin_amdgcn_s_barrier();            // B3: v ready

        // ---- D: dot from registers x shared v (R15-exact FP order) ----
        float acc = 0.0f;
        {
            const float4* Vr = (const float4*)v_lds + h * (HC / 4);
#pragma unroll
            for (int i = 0; i < 4; ++i) {
                float4 vvv = Vr[lane + i * 64];
                acc += wc[i].x * mc[i].x * vvv.x;
                acc += wc[i].y * mc[i].y * vvv.y;
                acc += wc[i].z * mc[i].z * vvv.z;
                acc += wc[i].w * mc[i].w * vvv.w;
            }
        }
        acc += __shfl_down(acc, 32);
        acc += __shfl_down(acc, 16);
        acc += __shfl_down(acc, 8);
        acc += __shfl_down(acc, 4);
        acc += __shfl_down(acc, 2);
        acc += __shfl_down(acc, 1);
        if (lane == 0) wsum[w] = acc;
        asm volatile("s_waitcnt lgkmcnt(0)" ::: "memory");
        SB0();
        __builtin_amdgcn_s_barrier();            // B4: wsum ready

        // ---- E: combine 2 partials + bias, publish (threads 0..7) ----
        if (t < RPB) {
            float s = wsum[2 * t] + wsum[2 * t + 1] + bias;
            float o = (l == N_LAYERS - 1) ? s : s / (1.0f + expf(-s));
            int tb = myidx + WIDTH;
            publish(vals + tb, o, E);
            if (tb >= NUM_NEURONS - WIDTH)
                __hip_atomic_store(out + (tb - (NUM_NEURONS - WIDTH)), o,
                                   __ATOMIC_RELAXED, __HIP_MEMORY_SCOPE_AGENT);
        }
        SB0();

        myidx = myidx_nxt;
        bias  = bias_nxt;
    }

    // ---- epilogue: advance epoch for the next launch (1 add per block) ----
    if (ctrl && t == 0)
        __hip_atomic_fetch_add(&ctrl[1], 1ull, __ATOMIC_RELAXED,
                               __HIP_MEMORY_SCOPE_AGENT);
}

// ---------- fallback (tiny d_ws): round-1 multi-kernel path, proven ----------
__global__ void init_values(const float* __restrict__ x, float* __restrict__ values) {
    int i = blockIdx.x * blockDim.x + threadIdx.x;
    if (i < NUM_NEURONS) values[i] = (i < WIDTH) ? x[i] : 0.0f;
}
template <bool LAST>
__global__ __launch_bounds__(256) void layer_kernel(
    const float* __restrict__ W, const float* __restrict__ M,
    const float* __restrict__ B, const int* __restrict__ idx,
    float* __restrict__ values)
{
    __shared__ float v_lds[WIDTH];
    __shared__ float ws2[4];
    const int t = threadIdx.x, row = blockIdx.x;
    {
        const int4* idx4 = (const int4*)idx;
        int4 ia = idx4[2 * t], ib = idx4[2 * t + 1];
        float4 va, vb;
        va.x = values[ia.x]; va.y = values[ia.y]; va.z = values[ia.z]; va.w = values[ia.w];
        vb.x = values[ib.x]; vb.y = values[ib.y]; vb.z = values[ib.z]; vb.w = values[ib.w];
        ((float4*)v_lds)[2 * t] = va;
        ((float4*)v_lds)[2 * t + 1] = vb;
    }
    __syncthreads();
    const float4* Wr = (const float4*)(W + (size_t)row * WIDTH);
    const float4* Mr = (const float4*)(M + (size_t)row * WIDTH);
    const float4* Vr = (const float4*)v_lds;
    float acc = 0.0f;
#pragma unroll
    for (int k = 0; k < 2; ++k) {
        int c = t + k * 256;
        float4 w = Wr[c], m = Mr[c], v = Vr[c];
        acc += w.x * m.x * v.x; acc += w.y * m.y * v.y;
        acc += w.z * m.z * v.z; acc += w.w * m.w * v.w;
    }
    acc += __shfl_down(acc, 32); acc += __shfl_down(acc, 16);
    acc += __shfl_down(acc, 8);  acc += __shfl_down(acc, 4);
    acc += __shfl_down(acc, 2);  acc += __shfl_down(acc, 1);
    if ((t & 63) == 0) ws2[t >> 6] = acc;
    __syncthreads();
    if (t == 0) {
        float s = ws2[0] + ws2[1] + ws2[2] + ws2[3] + B[row];
        values[idx[row] + WIDTH] = LAST ? s : s / (1.0f + expf(-s));
    }
}
__global__ void copy_out(const float* __restrict__ src, float* __restrict__ dst) {
    int i = blockIdx.x * blockDim.x + threadIdx.x;
    if (i < WIDTH) dst[i] = src[i];
}

extern "C" void kernel_launch(void* const* d_in, const int* in_sizes, int n_in,
                              void* d_out, int out_size, void* d_ws, size_t ws_size,
                              hipStream_t stream) {
    const float* x   = (const float*)d_in[0];
    const float* W   = (const float*)d_in[1];
    const float* M   = (const float*)d_in[2];
    const float* B   = (const float*)d_in[3];
    const int*   IDX = (const int*)d_in[4];
    float* out = (float*)d_out;

    if (ws_size >= WS_EPOCH_NEEDED) {
        u64* vals = (u64*)d_ws;
        prep<<<64, 256, 0, stream>>>(vals);
        mlp_flow<<<NB, NT, 0, stream>>>(x, W, M, B, IDX, vals,
                                        vals + NUM_NEURONS, out);
    } else if (ws_size >= WS_NEEDED) {
        u64* vals = (u64*)d_ws;
        hipMemsetAsync(vals, 0, WS_NEEDED, stream);
        mlp_flow<<<NB, NT, 0, stream>>>(x, W, M, B, IDX, vals, nullptr, out);
    } else {
        float* values = (float*)d_ws;
        init_values<<<(NUM_NEURONS + 255) / 256, 256, 0, stream>>>(x, values);
        for (int l = 0; l < N_LAYERS; ++l) {
            const float* Wl = W + (size_t)l * LAYER_ELEMS;
            const float* Ml = M + (size_t)l * LAYER_ELEMS;
            const float* Bl = B + (size_t)l * WIDTH;
            const int*   Il = IDX + (size_t)l * WIDTH;
            if (l < N_LAYERS - 1)
                layer_kernel<false><<<WIDTH, 256, 0, stream>>>(Wl, Ml, Bl, Il, values);
            else
                layer_kernel<true><<<WIDTH, 256, 0, stream>>>(Wl, Ml, Bl, Il, values);
        }
        copy_out<<<(WIDTH + 255) / 256, 256, 0, stream>>>(values + NUM_NEURONS - WIDTH, out);
    }
}

// Round 4
// 171.987 us; speedup vs baseline: 1.0481x; 1.0481x over previous
//
#include <hip/hip_runtime.h>

#define WIDTH 2048
#define N_LAYERS 24
#define NUM_NEURONS ((N_LAYERS + 1) * WIDTH)
#define NB 256           // 1 block/CU
#define NT 1024          // 16 waves
#define RPB 8            // rows per block
#define HC 1024          // half-row cols owned by one wave
#define HHC 512          // half of HC (pipeline granule)
#define LAYER_ELEMS ((size_t)WIDTH * WIDTH)

typedef unsigned long long u64;
#define WS_NEEDED (NUM_NEURONS * sizeof(u64))
#define WS_EPOCH_NEEDED (WS_NEEDED + 64)
#define MAGIC_V 0x7E57C0DE5EED0001ull
#define SB0() __builtin_amdgcn_sched_barrier(0)

// ---- dataflow primitives: (tag<<32 | f32bits) in one 8B agent atomic ----
__device__ __forceinline__ u64 vload(const u64* p) {
    return __hip_atomic_load(p, __ATOMIC_RELAXED, __HIP_MEMORY_SCOPE_AGENT);
}
__device__ __forceinline__ float resolve(const u64* p, u64 v, unsigned E) {
    while ((unsigned)(v >> 32) != E) {
        __builtin_amdgcn_s_sleep(1);
        v = __hip_atomic_load(p, __ATOMIC_RELAXED, __HIP_MEMORY_SCOPE_AGENT);
    }
    union { unsigned u; float f; } c; c.u = (unsigned)v; return c.f;
}
__device__ __forceinline__ void publish(u64* p, float f, unsigned E) {
    union { float f; unsigned u; } c; c.f = f;
    __hip_atomic_store(p, ((u64)E << 32) | (u64)c.u, __ATOMIC_RELAXED,
                       __HIP_MEMORY_SCOPE_AGENT);
}

// Async global->LDS staging (no dest registers; regalloc-proof).
__device__ __forceinline__ void gload_lds16(const void* g, void* l) {
    __builtin_amdgcn_global_load_lds(
        (const __attribute__((address_space(1))) void*)g,
        (__attribute__((address_space(3))) void*)l, 16, 0, 0);
}

// Stage HALF a wave-slice (row r, half h of the row, sub-half 'half'):
// 2KB W + 2KB M = 4 gloads. Ledger: exactly 4 vmem ops.
__device__ __forceinline__ void stage_half(const float* Wl, const float* Ml,
                                           float* bw, float* bm,
                                           int r, int h, int half, int lane) {
    const float* ws = Wl + (size_t)r * WIDTH + h * HC + half * HHC + lane * 4;
    const float* ms = Ml + (size_t)r * WIDTH + h * HC + half * HHC + lane * 4;
    char* wd = (char*)bw + lane * 16;
    char* md = (char*)bm + lane * 16;
    gload_lds16(ws,       wd);
    gload_lds16(ms,       md);
    gload_lds16(ws + 256, wd + 1024);
    gload_lds16(ms + 256, md + 1024);
}

// prep: idempotent workspace init (re-zeros when ws was poisoned).
__global__ __launch_bounds__(256) void prep(u64* __restrict__ vals) {
    u64* ctrl = vals + NUM_NEURONS;   // [0]=magic, [1]=done
    if (__hip_atomic_load(&ctrl[0], __ATOMIC_RELAXED,
                          __HIP_MEMORY_SCOPE_AGENT) == MAGIC_V)
        return;
    int i = blockIdx.x * blockDim.x + threadIdx.x;
    int stride = gridDim.x * blockDim.x;
    for (int e = i; e < NUM_NEURONS; e += stride)
        __hip_atomic_store(&vals[e], 0ull, __ATOMIC_RELAXED,
                           __HIP_MEMORY_SCOPE_AGENT);
    if (i == 0) {
        __hip_atomic_store(&ctrl[1], 0ull, __ATOMIC_RELAXED,
                           __HIP_MEMORY_SCOPE_AGENT);
        __hip_atomic_store(&ctrl[0], MAGIC_V, __ATOMIC_RELAXED,
                           __HIP_MEMORY_SCOPE_AGENT);
    }
}

__global__ __launch_bounds__(NT, 4) void mlp_flow(
    const float* __restrict__ x,
    const float* __restrict__ W,
    const float* __restrict__ M,
    const float* __restrict__ B,
    const int*   __restrict__ IDX,
    u64* __restrict__ vals,          // [NUM_NEURONS] (tag,value)
    u64* __restrict__ ctrl,          // epoch ctrl block, or nullptr (legacy)
    float* __restrict__ out)
{
    // double-buffered HALF-slice landing zones: H0 -> buf0, H1 -> buf1
    __shared__ float bufW0[16][HHC];  // 32KB
    __shared__ float bufM0[16][HHC];  // 32KB
    __shared__ float bufW1[16][HHC];  // 32KB
    __shared__ float bufM1[16][HHC];  // 32KB
    __shared__ float v_lds[WIDTH];    // 8KB
    __shared__ float wsum[16];
    __shared__ int   sI_[N_LAYERS * RPB];   // per-layer output ids (768B)
    __shared__ float sB_[N_LAYERS * RPB];   // per-layer biases    (768B)

    const int t    = threadIdx.x;
    const int w    = t >> 6;          // wave 0..15
    const int lane = t & 63;
    const int r    = w >> 1;          // row-in-block 0..7
    const int h    = w & 1;           // K-half 0/1
    const int bid  = blockIdx.x;
    const size_t block_off = (size_t)bid * RPB * WIDTH;

    // ---- epoch: E = launch index + 1, from persistent done-counter ----
    unsigned E = 1u;
    if (ctrl) {
        u64 d = vload(&ctrl[1]);
        E = (unsigned)(d >> 8) + 1u;   // done == 256 * launches_completed
    }

    // ---- prologue: zero out slice; once performed, publish input slice ----
    if (t < RPB)
        __hip_atomic_store(out + bid * RPB + t, 0.0f, __ATOMIC_RELAXED,
                           __HIP_MEMORY_SCOPE_AGENT);
    asm volatile("s_waitcnt vmcnt(0)" ::: "memory");
    if (t < RPB) {
        int g = bid * RPB + t;
        publish(vals + g, x[g], E);
    }

    // ---- scalar tables to LDS (keeps the loop's vmem ledger clean) ----
    if (t < N_LAYERS * RPB) {
        int ll = t >> 3, jj = t & 7;
        int gi = ll * WIDTH + bid * RPB + jj;
        sI_[t] = IDX[gi];
        sB_[t] = B[gi];
    }
    int2 I_cur = ((const int2*)IDX)[t];

    // ---- stage layer 0, both halves (ledger: 8 outstanding) ----
    SB0();
    stage_half(W + block_off, M + block_off, bufW0[w], bufM0[w], r, h, 0, lane);
    stage_half(W + block_off, M + block_off, bufW1[w], bufM1[w], r, h, 1, lane);
    SB0();

    for (int l = 0; l < N_LAYERS; ++l) {
        const bool last = (l + 1 == N_LAYERS);
        const int  ln   = last ? 0 : l + 1;            // wrap (reads unused)
        const float* Wn = W + (size_t)ln * LAYER_ELEMS + block_off;
        const float* Mn = M + (size_t)ln * LAYER_ELEMS + block_off;

        float4 wc0, wc1, wc2, wc3, mc0, mc1, mc2, mc3;

        // ---- H0 step: wait own H0 only (H1 + next stay in flight) ----
        asm volatile("s_waitcnt vmcnt(4)" ::: "memory");
        SB0();
        {
            const float4* W0 = (const float4*)bufW0[w];
            const float4* M0 = (const float4*)bufM0[w];
            wc0 = W0[lane]; wc1 = W0[lane + 64];
            mc0 = M0[lane]; mc1 = M0[lane + 64];
        }
        asm volatile("s_waitcnt lgkmcnt(0)" ::: "memory");
        SB0();
        if (!last)
            stage_half(Wn, Mn, bufW0[w], bufM0[w], r, h, 0, lane);
        SB0();

        // ---- H1 step: wait own H1 (next-H0's 4 loads stay in flight) ----
        if (!last) { asm volatile("s_waitcnt vmcnt(4)" ::: "memory"); }
        else       { asm volatile("s_waitcnt vmcnt(0)" ::: "memory"); }
        SB0();
        {
            const float4* W1 = (const float4*)bufW1[w];
            const float4* M1 = (const float4*)bufM1[w];
            wc2 = W1[lane]; wc3 = W1[lane + 64];
            mc2 = M1[lane]; mc3 = M1[lane + 64];
        }
        // polls (R0 timing: after full slice resident) + next-index load
        u64 pa = vload(vals + I_cur.x);
        u64 pb = vload(vals + I_cur.y);
        int2 I_next = ((const int2*)(IDX + ln * WIDTH))[t];
        asm volatile("s_waitcnt lgkmcnt(0)" ::: "memory");
        SB0();
        if (!last)
            stage_half(Wn, Mn, bufW1[w], bufM1[w], r, h, 1, lane);
        SB0();

        // ---- resolve (first check: counted wait; next stream in flight) ----
        float a = resolve(vals + I_cur.x, pa, E);
        float b = resolve(vals + I_cur.y, pb, E);
        v_lds[2 * t]     = a;
        v_lds[2 * t + 1] = b;
        asm volatile("s_waitcnt lgkmcnt(0)" ::: "memory");
        SB0();
        __builtin_amdgcn_s_barrier();        // #1: v ready

        // ---- dot (R0-exact FP order) ----
        float acc = 0.0f;
        {
            const float4* Vr = (const float4*)v_lds + h * (HC / 4);
            float4 v0 = Vr[lane];
            acc += wc0.x * mc0.x * v0.x;
            acc += wc0.y * mc0.y * v0.y;
            acc += wc0.z * mc0.z * v0.z;
            acc += wc0.w * mc0.w * v0.w;
            float4 v1 = Vr[lane + 64];
            acc += wc1.x * mc1.x * v1.x;
            acc += wc1.y * mc1.y * v1.y;
            acc += wc1.z * mc1.z * v1.z;
            acc += wc1.w * mc1.w * v1.w;
            float4 v2 = Vr[lane + 128];
            acc += wc2.x * mc2.x * v2.x;
            acc += wc2.y * mc2.y * v2.y;
            acc += wc2.z * mc2.z * v2.z;
            acc += wc2.w * mc2.w * v2.w;
            float4 v3 = Vr[lane + 192];
            acc += wc3.x * mc3.x * v3.x;
            acc += wc3.y * mc3.y * v3.y;
            acc += wc3.z * mc3.z * v3.z;
            acc += wc3.w * mc3.w * v3.w;
        }

        // ---- 64-lane reduce -> 1 partial per wave ----
        acc += __shfl_down(acc, 32);
        acc += __shfl_down(acc, 16);
        acc += __shfl_down(acc, 8);
        acc += __shfl_down(acc, 4);
        acc += __shfl_down(acc, 2);
        acc += __shfl_down(acc, 1);
        if (lane == 0) wsum[w] = acc;
        asm volatile("s_waitcnt lgkmcnt(0)" ::: "memory");
        SB0();
        __builtin_amdgcn_s_barrier();        // #2: wsum ready; v consumed

        // ---- combine 2 partials + bias, publish (threads 0..7) ----
        if (t < RPB) {
            float s = wsum[2 * t] + wsum[2 * t + 1] + sB_[l * RPB + t];
            float o = last ? s : s / (1.0f + expf(-s));
            int tb = sI_[l * RPB + t] + WIDTH;
            publish(vals + tb, o, E);
            if (tb >= NUM_NEURONS - WIDTH)
                __hip_atomic_store(out + (tb - (NUM_NEURONS - WIDTH)), o,
                                   __ATOMIC_RELAXED, __HIP_MEMORY_SCOPE_AGENT);
        }
        SB0();

        I_cur = I_next;
    }

    // ---- epilogue: advance epoch for the next launch (1 add per block) ----
    if (ctrl && t == 0)
        __hip_atomic_fetch_add(&ctrl[1], 1ull, __ATOMIC_RELAXED,
                               __HIP_MEMORY_SCOPE_AGENT);
}

// ---------- fallback (tiny d_ws): round-1 multi-kernel path, proven ----------
__global__ void init_values(const float* __restrict__ x, float* __restrict__ values) {
    int i = blockIdx.x * blockDim.x + threadIdx.x;
    if (i < NUM_NEURONS) values[i] = (i < WIDTH) ? x[i] : 0.0f;
}
template <bool LAST>
__global__ __launch_bounds__(256) void layer_kernel(
    const float* __restrict__ W, const float* __restrict__ M,
    const float* __restrict__ B, const int* __restrict__ idx,
    float* __restrict__ values)
{
    __shared__ float v_lds[WIDTH];
    __shared__ float ws2[4];
    const int t = threadIdx.x, row = blockIdx.x;
    {
        const int4* idx4 = (const int4*)idx;
        int4 ia = idx4[2 * t], ib = idx4[2 * t + 1];
        float4 va, vb;
        va.x = values[ia.x]; va.y = values[ia.y]; va.z = values[ia.z]; va.w = values[ia.w];
        vb.x = values[ib.x]; vb.y = values[ib.y]; vb.z = values[ib.z]; vb.w = values[ib.w];
        ((float4*)v_lds)[2 * t] = va;
        ((float4*)v_lds)[2 * t + 1] = vb;
    }
    __syncthreads();
    const float4* Wr = (const float4*)(W + (size_t)row * WIDTH);
    const float4* Mr = (const float4*)(M + (size_t)row * WIDTH);
    const float4* Vr = (const float4*)v_lds;
    float acc = 0.0f;
#pragma unroll
    for (int k = 0; k < 2; ++k) {
        int c = t + k * 256;
        float4 w = Wr[c], m = Mr[c], v = Vr[c];
        acc += w.x * m.x * v.x; acc += w.y * m.y * v.y;
        acc += w.z * m.z * v.z; acc += w.w * m.w * v.w;
    }
    acc += __shfl_down(acc, 32); acc += __shfl_down(acc, 16);
    acc += __shfl_down(acc, 8);  acc += __shfl_down(acc, 4);
    acc += __shfl_down(acc, 2);  acc += __shfl_down(acc, 1);
    if ((t & 63) == 0) ws2[t >> 6] = acc;
    __syncthreads();
    if (t == 0) {
        float s = ws2[0] + ws2[1] + ws2[2] + ws2[3] + B[row];
        values[idx[row] + WIDTH] = LAST ? s : s / (1.0f + expf(-s));
    }
}
__global__ void copy_out(const float* __restrict__ src, float* __restrict__ dst) {
    int i = blockIdx.x * blockDim.x + threadIdx.x;
    if (i < WIDTH) dst[i] = src[i];
}

extern "C" void kernel_launch(void* const* d_in, const int* in_sizes, int n_in,
                              void* d_out, int out_size, void* d_ws, size_t ws_size,
                              hipStream_t stream) {
    const float* x   = (const float*)d_in[0];
    const float* W   = (const float*)d_in[1];
    const float* M   = (const float*)d_in[2];
    const float* B   = (const float*)d_in[3];
    const int*   IDX = (const int*)d_in[4];
    float* out = (float*)d_out;

    if (ws_size >= WS_EPOCH_NEEDED) {
        u64* vals = (u64*)d_ws;
        prep<<<64, 256, 0, stream>>>(vals);
        mlp_flow<<<NB, NT, 0, stream>>>(x, W, M, B, IDX, vals,
                                        vals + NUM_NEURONS, out);
    } else if (ws_size >= WS_NEEDED) {
        u64* vals = (u64*)d_ws;
        hipMemsetAsync(vals, 0, WS_NEEDED, stream);
        mlp_flow<<<NB, NT, 0, stream>>>(x, W, M, B, IDX, vals, nullptr, out);
    } else {
        float* values = (float*)d_ws;
        init_values<<<(NUM_NEURONS + 255) / 256, 256, 0, stream>>>(x, values);
        for (int l = 0; l < N_LAYERS; ++l) {
            const float* Wl = W + (size_t)l * LAYER_ELEMS;
            const float* Ml = M + (size_t)l * LAYER_ELEMS;
            const float* Bl = B + (size_t)l * WIDTH;
            const int*   Il = IDX + (size_t)l * WIDTH;
            if (l < N_LAYERS - 1)
                layer_kernel<false><<<WIDTH, 256, 0, stream>>>(Wl, Ml, Bl, Il, values);
            else
                layer_kernel<true><<<WIDTH, 256, 0, stream>>>(Wl, Ml, Bl, Il, values);
        }
        copy_out<<<(WIDTH + 255) / 256, 256, 0, stream>>>(values + NUM_NEURONS - WIDTH, out);
    }
}